// Round 6
// baseline (319.563 us; speedup 1.0000x reference)
//
#include <hip/hip_runtime.h>
#include <math.h>

#define SSM_N 64
#define SSM_H 1024
#define SSM_L 2048
#define SSM_B 8
#define FFTN 2048
#define NT 256
#define KFS 2052   // row stride (f2) for Kf, 2049 used

// XOR swizzle on float2 index: touches bits 0-3 only, so PSWZ(a+256q)=PSWZ(a)+256q.
#define PSWZ(a) ((a) ^ (((a) >> 4) & 15))

typedef float f2 __attribute__((ext_vector_type(2)));
static __device__ __forceinline__ f2 mkf2(float a, float b){ f2 v; v.x = a; v.y = b; return v; }

static __device__ __forceinline__ f2 cmul(f2 a, f2 b){
  return mkf2(-a.y, a.y) * mkf2(b.y, b.x) + mkf2(a.x, a.x) * b;
}
static __device__ __forceinline__ f2 cconj(f2 a){ return mkf2(a.x, -a.y); }

template<bool INV> static __device__ __forceinline__ f2 mul_mi(f2 a){
  return INV ? mkf2(-a.y, a.x) : mkf2(a.y, -a.x);
}

// exp(-i*pi*k/8) table (cos, -sin)
#define W8C0 1.f
#define W8S0 0.f
#define W8C1 0.92387953251f
#define W8S1 (-0.38268343236f)
#define W8C2 0.70710678119f
#define W8S2 (-0.70710678119f)
#define W8C3 0.38268343236f
#define W8S3 (-0.92387953251f)
#define W8C4 0.f
#define W8S4 (-1.f)
#define W8C5 (-0.38268343236f)
#define W8S5 (-0.92387953251f)
#define W8C6 (-0.70710678119f)
#define W8S6 (-0.70710678119f)
#define W8C7 (-0.92387953251f)
#define W8S7 (-0.38268343236f)

// twiddle fetch from 1024-entry table: w = exp(-2pi*i*e/2048), e < 2048 always here.
template<bool INV> static __device__ __forceinline__ f2 twget(const f2* __restrict__ tw, int e){
  f2 w = tw[e & 1023];
  w = (e & 1024) ? -w : w;
  if (INV) w.y = -w.y;
  return w;
}

static __device__ __forceinline__ void init_tw1024(f2* tw, int t){
  #pragma unroll
  for (int i = 0; i < 4; ++i) {
    int e = t + 256*i;
    float s, c;
    sincosf(-6.2831853071795864769f * (float)e / (float)FFTN, &s, &c);
    tw[e] = mkf2(c, s);
  }
}

// In-place radix-8 Stockham stage, span S. reads; sync; writes; sync.
template<bool INV, int S, bool ZTOP>
static __device__ __forceinline__ void stage8_ip(f2* __restrict__ buf, const f2* __restrict__ tw,
                                                 int t, int st)
{
  f2 x[8];
  {
    const f2* sp = buf + st;
    if (ZTOP) {
      #pragma unroll
      for (int q = 0; q < 4; ++q) { x[q] = sp[256*q]; x[q+4] = mkf2(0.f, 0.f); }
    } else {
      #pragma unroll
      for (int q = 0; q < 8; ++q) x[q] = sp[256*q];
    }
  }
  __syncthreads();
  f2 t0=x[0]+x[4], t4=x[0]-x[4];
  f2 t1=x[1]+x[5], t5=x[1]-x[5];
  f2 t2=x[2]+x[6], t6=x[2]-x[6];
  f2 t3=x[3]+x[7], t7=x[3]-x[7];
  f2 b0=t0+t2, b2=t0-t2, b1=t1+t3, b3=t1-t3;
  f2 mb3 = mul_mi<INV>(b3);
  f2 y0=b0+b1, y4=b0-b1, y2=b2+mb3, y6=b2-mb3;
  const float r = 0.70710678118654752440f;
  f2 v1 = INV ? (r * mkf2(t5.x - t5.y, t5.y + t5.x)) : (r * mkf2(t5.x + t5.y, t5.y - t5.x));
  f2 v2 = mul_mi<INV>(t6);
  f2 v3 = INV ? (r * mkf2(-(t7.x + t7.y), t7.x - t7.y)) : (r * mkf2(t7.y - t7.x, -(t7.x + t7.y)));
  f2 a0=t4+v2, a2=t4-v2, a1=v1+v3, a3=v1-v3;
  f2 ma3 = mul_mi<INV>(a3);
  f2 y1=a0+a1, y5=a0-a1, y3=a2+ma3, y7=a2-ma3;
  int i = t & (S-1);
  int j = t - i;
  int base = i + j*8;
  buf[PSWZ(base)]     = y0;
  buf[PSWZ(base+S)]   = cmul(y1, twget<INV>(tw, j));
  buf[PSWZ(base+2*S)] = cmul(y2, twget<INV>(tw, 2*j));
  buf[PSWZ(base+3*S)] = cmul(y3, twget<INV>(tw, 3*j));
  buf[PSWZ(base+4*S)] = cmul(y4, twget<INV>(tw, 4*j));
  buf[PSWZ(base+5*S)] = cmul(y5, twget<INV>(tw, 5*j));
  buf[PSWZ(base+6*S)] = cmul(y6, twget<INV>(tw, 6*j));
  buf[PSWZ(base+7*S)] = cmul(y7, twget<INV>(tw, 7*j));
  __syncthreads();
}

// In-place final radix-4, span 512 (no twiddles).
template<bool INV, bool HALFOUT>
static __device__ __forceinline__ void stage4_ip(f2* __restrict__ buf, int st)
{
  f2 x[2][4];
  #pragma unroll
  for (int hh = 0; hh < 2; ++hh) {
    const f2* sp = buf + st + 256*hh;
    x[hh][0]=sp[0]; x[hh][1]=sp[512]; x[hh][2]=sp[1024]; x[hh][3]=sp[1536];
  }
  __syncthreads();
  #pragma unroll
  for (int hh = 0; hh < 2; ++hh) {
    f2 a0=x[hh][0]+x[hh][2], a2=x[hh][0]-x[hh][2];
    f2 a1=x[hh][1]+x[hh][3], a3=x[hh][1]-x[hh][3];
    f2 m = mul_mi<INV>(a3);
    f2* wp = buf + st + 256*hh;
    wp[0]   = a0+a1;
    wp[512] = a2+m;
    if (!HALFOUT) {
      wp[1024] = a0-a1;
      wp[1536] = a2-m;
    }
  }
  __syncthreads();
}

// 2048-pt FFT fully in place in `buf`. Leading sync covers caller's writes.
template<bool INV, bool ZTOP, bool HALFOUT>
static __device__ void fft_ip(f2* buf, const f2* tw, int t, int st)
{
  __syncthreads();
  stage8_ip<INV, 1, ZTOP>(buf, tw, t, st);
  stage8_ip<INV, 8, false>(buf, tw, t, st);
  stage8_ip<INV, 64, false>(buf, tw, t, st);
  stage4_ip<INV, HALFOUT>(buf, st);
}

// Launch 1: fat kernel — blocks [0,4096): (B,L,H)->(B,H,L) transpose; blocks [4096,4160): cden.
__global__ __launch_bounds__(256) void kprep(
    const float* __restrict__ r, float* __restrict__ rT,
    const float* __restrict__ B_re, const float* __restrict__ B_im,
    const float* __restrict__ P_re, const float* __restrict__ P_im,
    const float* __restrict__ Q_re, const float* __restrict__ Q_im,
    const float* __restrict__ diag_re, const float* __restrict__ diag_im,
    const float* __restrict__ step,
    f2* __restrict__ cdenT, f2* __restrict__ f2v, f2* __restrict__ facv)
{
  __shared__ float til[64][65];
  int bid = blockIdx.x;
  int t = threadIdx.x;
  if (bid < 4096) {
    int tx = t & 15, ty = t >> 4;
    int h0 = (bid & 15) * 64, l0 = ((bid >> 4) & 31) * 64, b = bid >> 9;
    const float4* s4 = (const float4*)(r + ((size_t)b*SSM_L + l0)*SSM_H + h0);
    #pragma unroll
    for (int i = 0; i < 4; ++i) {
      int lr = ty + 16*i;
      float4 v = s4[(size_t)lr*(SSM_H/4) + tx];
      til[lr][4*tx+0]=v.x; til[lr][4*tx+1]=v.y; til[lr][4*tx+2]=v.z; til[lr][4*tx+3]=v.w;
    }
    __syncthreads();
    float4* d4 = (float4*)(rT + ((size_t)b*SSM_H + h0)*SSM_L + l0);
    #pragma unroll
    for (int i = 0; i < 4; ++i) {
      int hr = ty + 16*i;
      float4 w;
      w.x = til[4*tx+0][hr]; w.y = til[4*tx+1][hr];
      w.z = til[4*tx+2][hr]; w.w = til[4*tx+3][hr];
      d4[(size_t)hr*(SSM_L/4) + tx] = w;
    }
  } else {
    int gid = (bid - 4096) * 256 + t;     // 16384 threads, 8 per l
    int l = gid >> 3, s = gid & 7;
    double stepc = (double)step[0]; if (stepc < 1e-6) stepc = 1e-6;
    double ang = -2.0 * 3.14159265358979323846 * (double)l / (double)SSM_L;
    double zr = cos(ang), zi = sin(ang);
    double dr = 1.0 + zr, di = zi;
    double nr = 1.0 - zr, ni = -zi;
    double den = dr*dr + di*di;
    double i2s = 2.0 / stepc;
    double gr = i2s * (nr*dr + ni*di) / den;
    double gi = i2s * (ni*dr - nr*di) / den;
    double k10r=0.0, k10i=0.0, k11r=0.0, k11i=0.0;
    #pragma unroll
    for (int q = 0; q < 8; ++q) {
      int n = s*8 + q;
      double ar = gr - (double)diag_re[n];
      double ai = gi - (double)diag_im[n];
      double d2 = ar*ar + ai*ai;
      double cr = ar/d2, ci = -ai/d2;
      cdenT[n*SSM_L + l] = mkf2((float)cr, (float)ci);
      double qr = (double)Q_re[n], qi = (double)Q_im[n];
      double br = (double)B_re[n], bi = (double)B_im[n];
      double pr = (double)P_re[n], pi = (double)P_im[n];
      double qbr = qr*br - qi*bi, qbi = qr*bi + qi*br;
      double qpr = qr*pr - qi*pi, qpi = qr*pi + qi*pr;
      k10r += qbr*cr - qbi*ci; k10i += qbr*ci + qbi*cr;
      k11r += qpr*cr - qpi*ci; k11i += qpr*ci + qpi*cr;
    }
    #pragma unroll
    for (int off = 1; off < 8; off <<= 1) {
      k10r += __shfl_xor(k10r, off);
      k10i += __shfl_xor(k10i, off);
      k11r += __shfl_xor(k11r, off);
      k11i += __shfl_xor(k11i, off);
    }
    if (s == 0) {
      f2v[l] = mkf2((float)(2.0*dr/den), (float)(-2.0*di/den));
      double er = 1.0 + k11r, ei = k11i;
      double ed = er*er + ei*ei;
      facv[l] = mkf2((float)((k10r*er + k10i*ei)/ed), (float)((k10i*er - k10r*ei)/ed));
    }
  }
}

// Launch 2: contraction (2 channels) + per-row: even Kf bins from at_roots,
// iFFT -> K, twist by exp(-i*pi*n/2048), fwd FFT (half out) -> odd Kf bins.
__global__ __launch_bounds__(NT, 2) void kkern(
    const float* __restrict__ C_re, const float* __restrict__ C_im,
    const float* __restrict__ B_re, const float* __restrict__ B_im,
    const float* __restrict__ P_re, const float* __restrict__ P_im,
    const f2* __restrict__ cdenT, const f2* __restrict__ f2v, const f2* __restrict__ facv,
    f2* __restrict__ Kf)
{
  __shared__ f2 bufA[FFTN];
  __shared__ f2 bufB[FFTN];
  __shared__ f2 tw[1024];
  int t = threadIdx.x, st = PSWZ(t);
  int h0 = blockIdx.x * 2;
  init_tw1024(tw, t);
  f2* cbs = bufA;   // alias: dead once at_roots rows are written
  if (t < 128) {
    int h = h0 + (t >> 6), n = t & 63;
    f2 cc = mkf2(C_re[h*SSM_N + n], C_im[h*SSM_N + n]);
    cbs[t]       = cmul(cc, mkf2(B_re[n], B_im[n]));
    cbs[128 + t] = cmul(cc, mkf2(P_re[n], P_im[n]));
  }
  __syncthreads();
  f2 k00[2][8], k01[2][8];
  #pragma unroll
  for (int h = 0; h < 2; ++h)
    #pragma unroll
    for (int i = 0; i < 8; ++i) { k00[h][i] = mkf2(0.f,0.f); k01[h][i] = mkf2(0.f,0.f); }
  for (int n = 0; n < SSM_N; ++n) {
    f2 cd[8];
    #pragma unroll
    for (int i = 0; i < 8; ++i) cd[i] = cdenT[n*SSM_L + t + i*NT];
    #pragma unroll
    for (int h = 0; h < 2; ++h) {
      f2 cb = cbs[h*64 + n], cp = cbs[128 + h*64 + n];
      #pragma unroll
      for (int i = 0; i < 8; ++i) {
        k00[h][i] = k00[h][i] + cmul(cb, cd[i]);
        k01[h][i] = k01[h][i] + cmul(cp, cd[i]);
      }
    }
  }
  __syncthreads();    // cbs dead
  #pragma unroll
  for (int i = 0; i < 8; ++i) {
    int l = t + i*NT;
    f2 fv = f2v[l], fc = facv[l];
    bufA[PSWZ(l)] = cmul(fv, k00[0][i] - cmul(k01[0][i], fc));
    bufB[PSWZ(l)] = cmul(fv, k00[1][i] - cmul(k01[1][i], fc));
  }
  __syncthreads();
  const float Wc8[8] = {W8C0,W8C1,W8C2,W8C3,W8C4,W8C5,W8C6,W8C7};
  const float Ws8[8] = {W8S0,W8S1,W8S2,W8S3,W8S4,W8S5,W8S6,W8S7};
  float sb, cb;
  sincosf(-3.14159265358979f * (float)t / (float)FFTN, &sb, &cb);
  f2 cbase = mkf2(cb, sb);
  for (int hh = 0; hh < 2; ++hh) {
    f2* buf = hh ? bufB : bufA;
    f2* krow = Kf + (size_t)(h0 + hh) * KFS;
    #pragma unroll
    for (int i = 0; i < 4; ++i) {               // even bins: Hermitian part of at_roots
      int m = t + i*NT;
      if (m == 0) {
        krow[0]    = mkf2(buf[0].x, 0.f);
        krow[FFTN] = mkf2(buf[PSWZ(FFTN/2)].x, 0.f);
      } else {
        krow[2*m] = 0.5f * (buf[PSWZ(m)] + cconj(buf[PSWZ(FFTN - m)]));
      }
    }
    fft_ip<true, false, false>(buf, tw, t, st);   // iFFT (unscaled): K*2048 in .x
    f2 tv[8];
    const float scale = 1.0f / (float)FFTN;
    #pragma unroll
    for (int i = 0; i < 8; ++i) {
      int n = t + i*NT;
      float K = buf[PSWZ(n)].x * scale;
      tv[i] = K * cmul(cbase, mkf2(Wc8[i], Ws8[i]));
    }
    __syncthreads();
    #pragma unroll
    for (int i = 0; i < 8; ++i) buf[PSWZ(t + i*NT)] = tv[i];
    fft_ip<false, false, true>(buf, tw, t, st);   // odd bins (lower half)
    #pragma unroll
    for (int i = 0; i < 4; ++i) {
      int m = t + i*NT;
      krow[2*m+1] = buf[PSWZ(m)];
    }
  }
}

// Launch 3: per (b,h) row in rT: rfft4096 (packed) -> *Kf -> irfft4096 + D*r.
__global__ __launch_bounds__(NT, 6) void kconv(float* __restrict__ rT, const f2* __restrict__ Kf,
                                               const float* __restrict__ Dp)
{
  __shared__ f2 buf[FFTN];
  __shared__ f2 tw[1024];
  int t = threadIdx.x, st = PSWZ(t);
  int row = blockIdx.x;
  int h = row & (SSM_H - 1);
  float Dv = Dp[0];
  init_tw1024(tw, t);
  float* rrow = rT + (size_t)row * SSM_L;
  const float4* r4 = (const float4*)rrow;
  #pragma unroll
  for (int i = 0; i < 2; ++i) {                  // 2048 reals -> lower 1024 packed f2
    int j2 = t + i*NT;
    float4 v = r4[j2];
    buf[PSWZ(2*j2)]   = mkf2(v.x, v.y);
    buf[PSWZ(2*j2+1)] = mkf2(v.z, v.w);
  }
  fft_ip<false, true, false>(buf, tw, t, st);    // spectrum in buf
  const f2* krow = Kf + (size_t)h * KFS;
  float sb, cb;
  sincosf(-3.14159265358979f * (float)t / (float)FFTN, &sb, &cb);
  f2 base = mkf2(cb, sb);
  f2 outk[4], outkk[4];
  {
    const float Wc[4] = {W8C0,W8C1,W8C2,W8C3};
    const float Ws[4] = {W8S0,W8S1,W8S2,W8S3};
    #pragma unroll
    for (int i = 0; i < 4; ++i) {                // read + compute phase
      int k = t + i*NT;
      f2 w = cmul(base, mkf2(Wc[i], Ws[i]));     // exp(-i*pi*k/2048)
      float c = w.x, s = w.y;
      if (k == 0) {
        f2 c0 = buf[0];
        float F0 = c0.x + c0.y, Fn = c0.x - c0.y;
        f2 G0 = F0 * krow[0];
        f2 Gn = Fn * krow[FFTN];
        f2 Xe = 0.5f * (G0 + Gn);
        f2 Xo = 0.5f * (G0 - Gn);
        outk[0]  = mkf2(Xe.x - Xo.y, Xe.y + Xo.x);
        outkk[0] = cconj(cmul(cconj(buf[PSWZ(FFTN/2)]), krow[FFTN/2]));
      } else {
        int kk = FFTN - k;
        f2 Ck = buf[PSWZ(k)], Ckk = buf[PSWZ(kk)];
        f2 E = mkf2(0.5f*(Ck.x + Ckk.x), 0.5f*(Ck.y - Ckk.y));
        f2 O = mkf2(0.5f*(Ck.y + Ckk.y), 0.5f*(Ckk.x - Ck.x));
        f2 Fk  = E + cmul(mkf2(c, s), O);
        f2 Fkk = cconj(E) + cmul(mkf2(-c, s), cconj(O));
        f2 Gk  = cmul(Fk,  krow[k]);
        f2 Gkk = cmul(Fkk, krow[kk]);
        f2 Xe  = mkf2(0.5f*(Gk.x + Gkk.x), 0.5f*(Gk.y - Gkk.y));
        f2 Dd  = mkf2(0.5f*(Gk.x - Gkk.x), 0.5f*(Gk.y + Gkk.y));
        f2 Xo  = cmul(mkf2(c, -s), Dd);          // conj(w) * Dd
        outk[i] = mkf2(Xe.x - Xo.y, Xe.y + Xo.x);
        f2 Xe2 = mkf2(0.5f*(Gkk.x + Gk.x), 0.5f*(Gkk.y - Gk.y));
        f2 Dd2 = mkf2(0.5f*(Gkk.x - Gk.x), 0.5f*(Gkk.y + Gk.y));
        f2 Xo2 = cmul(mkf2(-c, -s), Dd2);        // -w * Dd2
        outkk[i] = mkf2(Xe2.x - Xo2.y, Xe2.y + Xo2.x);
      }
    }
  }
  __syncthreads();
  #pragma unroll
  for (int i = 0; i < 4; ++i) {                  // write phase
    int k = t + i*NT;
    if (k == 0) { buf[0] = outk[0]; buf[PSWZ(FFTN/2)] = outkk[0]; }
    else        { buf[PSWZ(k)] = outk[i]; buf[PSWZ(FFTN - k)] = outkk[i]; }
  }
  fft_ip<true, false, true>(buf, tw, t, st);     // result lower half
  const float sc = 1.0f / (float)FFTN;
  float4* w4 = (float4*)rrow;
  #pragma unroll
  for (int i = 0; i < 2; ++i) {
    int j2 = t + i*NT;
    float4 v = r4[j2];                           // re-read own input (L2-warm, pre-overwrite)
    f2 z0 = buf[PSWZ(2*j2)], z1 = buf[PSWZ(2*j2+1)];
    w4[j2] = make_float4(z0.x*sc + Dv*v.x, z0.y*sc + Dv*v.y,
                         z1.x*sc + Dv*v.z, z1.y*sc + Dv*v.w);
  }
}

// Launch 4: (B,H,L) -> (B,L,H) transpose + exact GELU
__global__ __launch_bounds__(256) void ktback(const float* __restrict__ yT, float* __restrict__ out)
{
  __shared__ float til[64][65];
  int t = threadIdx.x, tx = t & 15, ty = t >> 4;
  int h0 = blockIdx.x * 64, l0 = blockIdx.y * 64, b = blockIdx.z;
  const float4* s4 = (const float4*)(yT + ((size_t)b*SSM_H + h0)*SSM_L + l0);
  #pragma unroll
  for (int i = 0; i < 4; ++i) {
    int hr = ty + 16*i;
    float4 v = s4[(size_t)hr*(SSM_L/4) + tx];
    til[hr][4*tx+0]=v.x; til[hr][4*tx+1]=v.y; til[hr][4*tx+2]=v.z; til[hr][4*tx+3]=v.w;
  }
  __syncthreads();
  float4* d4 = (float4*)(out + ((size_t)b*SSM_L + l0)*SSM_H + h0);
  #pragma unroll
  for (int i = 0; i < 4; ++i) {
    int lr = ty + 16*i;
    float4 w;
    float x0 = til[4*tx+0][lr], x1 = til[4*tx+1][lr];
    float x2 = til[4*tx+2][lr], x3 = til[4*tx+3][lr];
    w.x = 0.5f * x0 * (1.0f + erff(x0 * 0.70710678118654752f));
    w.y = 0.5f * x1 * (1.0f + erff(x1 * 0.70710678118654752f));
    w.z = 0.5f * x2 * (1.0f + erff(x2 * 0.70710678118654752f));
    w.w = 0.5f * x3 * (1.0f + erff(x3 * 0.70710678118654752f));
    d4[(size_t)lr*(SSM_H/4) + tx] = w;
  }
}

extern "C" void kernel_launch(void* const* d_in, const int* in_sizes, int n_in,
                              void* d_out, int out_size, void* d_ws, size_t ws_size,
                              hipStream_t stream)
{
  const float* r       = (const float*)d_in[0];
  const float* B_re    = (const float*)d_in[1];
  const float* B_im    = (const float*)d_in[2];
  const float* C_re    = (const float*)d_in[3];
  const float* C_im    = (const float*)d_in[4];
  const float* P_re    = (const float*)d_in[5];
  const float* P_im    = (const float*)d_in[6];
  const float* Q_re    = (const float*)d_in[7];
  const float* Q_im    = (const float*)d_in[8];
  const float* diag_re = (const float*)d_in[9];
  const float* diag_im = (const float*)d_in[10];
  const float* step    = (const float*)d_in[11];
  const float* Dp      = (const float*)d_in[12];
  float* out = (float*)d_out;

  char* p = (char*)d_ws;
  float* rT  = (float*)p; p += (size_t)SSM_B*SSM_H*SSM_L*sizeof(float);   // 64 MiB
  f2* cdenT  = (f2*)p;    p += (size_t)SSM_N*SSM_L*sizeof(f2);            // 1 MiB
  f2* f2v    = (f2*)p;    p += (size_t)SSM_L*sizeof(f2);
  f2* facv   = (f2*)p;    p += (size_t)SSM_L*sizeof(f2);
  f2* Kf     = (f2*)p;    p += (size_t)SSM_H*KFS*sizeof(f2);              // ~16.8 MiB

  kprep<<<4096 + 64, 256, 0, stream>>>(r, rT, B_re, B_im, P_re, P_im, Q_re, Q_im,
                                       diag_re, diag_im, step, cdenT, f2v, facv);
  kkern<<<SSM_H/2, NT, 0, stream>>>(C_re, C_im, B_re, B_im, P_re, P_im,
                                    cdenT, f2v, facv, Kf);
  kconv<<<SSM_B*SSM_H, NT, 0, stream>>>(rT, Kf, Dp);
  ktback<<<dim3(SSM_H/64, SSM_L/64, SSM_B), 256, 0, stream>>>(rT, out);
}

// Round 7
// 271.330 us; speedup vs baseline: 1.1778x; 1.1778x over previous
//
#include <hip/hip_runtime.h>
#include <math.h>

#define SSM_N 64
#define SSM_H 1024
#define SSM_L 2048
#define SSM_B 8
#define FFTN 2048
#define NT 256
#define KFS 2052   // row stride (f2) for Kf, 2049 used

// XOR swizzle on float2 index: touches bits 0-3 only, so PSWZ(a+256q)=PSWZ(a)+256q.
#define PSWZ(a) ((a) ^ (((a) >> 4) & 15))

typedef float f2 __attribute__((ext_vector_type(2)));
static __device__ __forceinline__ f2 mkf2(float a, float b){ f2 v; v.x = a; v.y = b; return v; }

static __device__ __forceinline__ f2 cmul(f2 a, f2 b){
  return mkf2(-a.y, a.y) * mkf2(b.y, b.x) + mkf2(a.x, a.x) * b;
}
static __device__ __forceinline__ f2 cconj(f2 a){ return mkf2(a.x, -a.y); }

template<bool INV> static __device__ __forceinline__ f2 mul_mi(f2 a){
  return INV ? mkf2(-a.y, a.x) : mkf2(a.y, -a.x);
}
template<bool INV> static __device__ __forceinline__ f2 mul_w81(f2 a){
  const float r = 0.70710678118654752440f;
  return INV ? (r * mkf2(a.x - a.y, a.y + a.x)) : (r * mkf2(a.x + a.y, a.y - a.x));
}
template<bool INV> static __device__ __forceinline__ f2 mul_w83(f2 a){
  const float r = 0.70710678118654752440f;
  return INV ? (r * mkf2(-(a.x + a.y), a.x - a.y)) : (r * mkf2(a.y - a.x, -(a.x + a.y)));
}

// exp(-i*pi*k/8) table (cos, -sin)
#define W8C0 1.f
#define W8S0 0.f
#define W8C1 0.92387953251f
#define W8S1 (-0.38268343236f)
#define W8C2 0.70710678119f
#define W8S2 (-0.70710678119f)
#define W8C3 0.38268343236f
#define W8S3 (-0.92387953251f)
#define W8C4 0.f
#define W8S4 (-1.f)
#define W8C5 (-0.38268343236f)
#define W8S5 (-0.92387953251f)
#define W8C6 (-0.70710678119f)
#define W8S6 (-0.70710678119f)
#define W8C7 (-0.92387953251f)
#define W8S7 (-0.38268343236f)

template<bool INV>
static __device__ __forceinline__ void bfly8_store(f2* __restrict__ dst, const f2* __restrict__ tw,
                                                   f2* x, int j, int base, int S)
{
  f2 t0=x[0]+x[4], t4=x[0]-x[4];
  f2 t1=x[1]+x[5], t5=x[1]-x[5];
  f2 t2=x[2]+x[6], t6=x[2]-x[6];
  f2 t3=x[3]+x[7], t7=x[3]-x[7];
  f2 b0=t0+t2, b2=t0-t2, b1=t1+t3, b3=t1-t3;
  f2 mb3 = mul_mi<INV>(b3);
  f2 y0=b0+b1, y4=b0-b1, y2=b2+mb3, y6=b2-mb3;
  f2 v1 = mul_w81<INV>(t5), v2 = mul_mi<INV>(t6), v3 = mul_w83<INV>(t7);
  f2 a0=t4+v2, a2=t4-v2, a1=v1+v3, a3=v1-v3;
  f2 ma3 = mul_mi<INV>(a3);
  f2 y1=a0+a1, y5=a0-a1, y3=a2+ma3, y7=a2-ma3;
  f2 w1 = tw[j];
  if (INV) w1.y = -w1.y;
  f2 w2 = cmul(w1,w1);
  f2 w3 = cmul(w2,w1);
  f2 w4 = cmul(w2,w2);
  f2 w5 = cmul(w3,w2);
  f2 w6 = cmul(w3,w3);
  f2 w7 = cmul(w4,w3);
  dst[PSWZ(base)]     = y0;
  dst[PSWZ(base+S)]   = cmul(y1,w1);
  dst[PSWZ(base+2*S)] = cmul(y2,w2);
  dst[PSWZ(base+3*S)] = cmul(y3,w3);
  dst[PSWZ(base+4*S)] = cmul(y4,w4);
  dst[PSWZ(base+5*S)] = cmul(y5,w5);
  dst[PSWZ(base+6*S)] = cmul(y6,w6);
  dst[PSWZ(base+7*S)] = cmul(y7,w7);
}

template<bool INV, bool ZTOP>
static __device__ __forceinline__ void stage8_first(const f2* __restrict__ src, f2* __restrict__ dst,
                                                    const f2* __restrict__ tw, int t, int st)
{
  const f2* sp = src + st;
  f2 x[8];
  if (ZTOP) {
    #pragma unroll
    for (int q = 0; q < 4; ++q) { x[q] = sp[256*q]; x[q+4] = mkf2(0.f, 0.f); }
  } else {
    #pragma unroll
    for (int q = 0; q < 8; ++q) x[q] = sp[256*q];
  }
  bfly8_store<INV>(dst, tw, x, t, t*8, 1);
}

template<bool INV, int S>
static __device__ __forceinline__ void stage8_mid(const f2* __restrict__ src, f2* __restrict__ dst,
                                                  const f2* __restrict__ tw, int t, int st)
{
  const f2* sp = src + st;
  f2 x[8];
  #pragma unroll
  for (int q = 0; q < 8; ++q) x[q] = sp[256*q];
  int i = t & (S-1);
  int j = t - i;
  bfly8_store<INV>(dst, tw, x, j, i + j*8, S);
}

template<bool INV, bool HALFOUT>
static __device__ __forceinline__ void stage4f(const f2* __restrict__ src, f2* __restrict__ dst, int st)
{
  #pragma unroll
  for (int hh = 0; hh < 2; ++hh) {
    const f2* sp = src + st + 256*hh;
    f2* wp = dst + st + 256*hh;
    f2 x0=sp[0], x1=sp[512], x2=sp[1024], x3=sp[1536];
    f2 a0=x0+x2, a2=x0-x2, a1=x1+x3, a3=x1-x3;
    f2 m = mul_mi<INV>(a3);
    wp[0]   = a0+a1;
    wp[512] = a2+m;
    if (!HALFOUT) {
      wp[1024] = a0-a1;
      wp[1536] = a2-m;
    }
  }
}

// 2048-pt FFT, swizzled layout; input A, result A, B scratch.
template<bool INV, bool ZTOP, bool HALFOUT>
static __device__ void fft2048(f2* A, f2* B, const f2* tw, int t, int st)
{
  __syncthreads();
  stage8_first<INV, ZTOP>(A, B, tw, t, st);
  __syncthreads();
  stage8_mid<INV, 8>(B, A, tw, t, st);
  __syncthreads();
  stage8_mid<INV, 64>(A, B, tw, t, st);
  __syncthreads();
  stage4f<INV, HALFOUT>(B, A, st);
  __syncthreads();
}

static __device__ __forceinline__ void init_tw(f2* tw, int t)
{
  float s, c;
  sincosf(-6.2831853071795864769f * (float)t / (float)FFTN, &s, &c);
  tw[t] = mkf2(c, s);   // exponents used are 0..248
}

// Launch 1: fat kernel — blocks [0,4096): (B,L,H)->(B,H,L) transpose; blocks [4096,4160): cden.
__global__ __launch_bounds__(256) void kprep(
    const float* __restrict__ r, float* __restrict__ rT,
    const float* __restrict__ B_re, const float* __restrict__ B_im,
    const float* __restrict__ P_re, const float* __restrict__ P_im,
    const float* __restrict__ Q_re, const float* __restrict__ Q_im,
    const float* __restrict__ diag_re, const float* __restrict__ diag_im,
    const float* __restrict__ step,
    f2* __restrict__ cdenT, f2* __restrict__ f2v, f2* __restrict__ facv)
{
  __shared__ float til[64][65];
  int bid = blockIdx.x;
  int t = threadIdx.x;
  if (bid < 4096) {
    int tx = t & 15, ty = t >> 4;
    int h0 = (bid & 15) * 64, l0 = ((bid >> 4) & 31) * 64, b = bid >> 9;
    const float4* s4 = (const float4*)(r + ((size_t)b*SSM_L + l0)*SSM_H + h0);
    #pragma unroll
    for (int i = 0; i < 4; ++i) {
      int lr = ty + 16*i;
      float4 v = s4[(size_t)lr*(SSM_H/4) + tx];
      til[lr][4*tx+0]=v.x; til[lr][4*tx+1]=v.y; til[lr][4*tx+2]=v.z; til[lr][4*tx+3]=v.w;
    }
    __syncthreads();
    float4* d4 = (float4*)(rT + ((size_t)b*SSM_H + h0)*SSM_L + l0);
    #pragma unroll
    for (int i = 0; i < 4; ++i) {
      int hr = ty + 16*i;
      float4 w;
      w.x = til[4*tx+0][hr]; w.y = til[4*tx+1][hr];
      w.z = til[4*tx+2][hr]; w.w = til[4*tx+3][hr];
      d4[(size_t)hr*(SSM_L/4) + tx] = w;
    }
  } else {
    int gid = (bid - 4096) * 256 + t;     // 16384 threads, 8 per l
    int l = gid >> 3, s = gid & 7;
    double stepc = (double)step[0]; if (stepc < 1e-6) stepc = 1e-6;
    double ang = -2.0 * 3.14159265358979323846 * (double)l / (double)SSM_L;
    double zr = cos(ang), zi = sin(ang);
    double dr = 1.0 + zr, di = zi;
    double nr = 1.0 - zr, ni = -zi;
    double den = dr*dr + di*di;
    double i2s = 2.0 / stepc;
    double gr = i2s * (nr*dr + ni*di) / den;
    double gi = i2s * (ni*dr - nr*di) / den;
    double k10r=0.0, k10i=0.0, k11r=0.0, k11i=0.0;
    #pragma unroll
    for (int q = 0; q < 8; ++q) {
      int n = s*8 + q;
      double ar = gr - (double)diag_re[n];
      double ai = gi - (double)diag_im[n];
      double d2 = ar*ar + ai*ai;
      double cr = ar/d2, ci = -ai/d2;
      cdenT[n*SSM_L + l] = mkf2((float)cr, (float)ci);
      double qr = (double)Q_re[n], qi = (double)Q_im[n];
      double br = (double)B_re[n], bi = (double)B_im[n];
      double pr = (double)P_re[n], pi = (double)P_im[n];
      double qbr = qr*br - qi*bi, qbi = qr*bi + qi*br;
      double qpr = qr*pr - qi*pi, qpi = qr*pi + qi*pr;
      k10r += qbr*cr - qbi*ci; k10i += qbr*ci + qbi*cr;
      k11r += qpr*cr - qpi*ci; k11i += qpr*ci + qpi*cr;
    }
    #pragma unroll
    for (int off = 1; off < 8; off <<= 1) {
      k10r += __shfl_xor(k10r, off);
      k10i += __shfl_xor(k10i, off);
      k11r += __shfl_xor(k11r, off);
      k11i += __shfl_xor(k11i, off);
    }
    if (s == 0) {
      f2v[l] = mkf2((float)(2.0*dr/den), (float)(-2.0*di/den));
      double er = 1.0 + k11r, ei = k11i;
      double ed = er*er + ei*ei;
      facv[l] = mkf2((float)((k10r*er + k10i*ei)/ed), (float)((k10i*er - k10r*ei)/ed));
    }
  }
}

// Launch 2: contraction (2 channels) then per channel: even Kf bins (Hermitian part of
// at_roots), iFFT -> K, twist by exp(-i*pi*n/2048), fwd FFT (half out) -> odd Kf bins.
// Dual-buffer FFT; channel 1's accumulators stay in registers during channel 0's FFTs.
__global__ __launch_bounds__(NT, 2) void kkern(
    const float* __restrict__ C_re, const float* __restrict__ C_im,
    const float* __restrict__ B_re, const float* __restrict__ B_im,
    const float* __restrict__ P_re, const float* __restrict__ P_im,
    const f2* __restrict__ cdenT, const f2* __restrict__ f2v, const f2* __restrict__ facv,
    f2* __restrict__ Kf)
{
  __shared__ f2 bufA[FFTN];
  __shared__ f2 bufB[FFTN];
  __shared__ f2 tw[256];
  int t = threadIdx.x, st = PSWZ(t);
  int h0 = blockIdx.x * 2;
  init_tw(tw, t);
  f2* cbs = bufA;   // alias: dead once at_roots writes begin
  if (t < 128) {
    int h = h0 + (t >> 6), n = t & 63;
    f2 cc = mkf2(C_re[h*SSM_N + n], C_im[h*SSM_N + n]);
    cbs[t]       = cmul(cc, mkf2(B_re[n], B_im[n]));
    cbs[128 + t] = cmul(cc, mkf2(P_re[n], P_im[n]));
  }
  __syncthreads();
  f2 k00[2][8], k01[2][8];
  #pragma unroll
  for (int h = 0; h < 2; ++h)
    #pragma unroll
    for (int i = 0; i < 8; ++i) { k00[h][i] = mkf2(0.f,0.f); k01[h][i] = mkf2(0.f,0.f); }
  for (int n = 0; n < SSM_N; ++n) {
    f2 cd[8];
    #pragma unroll
    for (int i = 0; i < 8; ++i) cd[i] = cdenT[n*SSM_L + t + i*NT];
    #pragma unroll
    for (int h = 0; h < 2; ++h) {
      f2 cb = cbs[h*64 + n], cp = cbs[128 + h*64 + n];
      #pragma unroll
      for (int i = 0; i < 8; ++i) {
        k00[h][i] = k00[h][i] + cmul(cb, cd[i]);
        k01[h][i] = k01[h][i] + cmul(cp, cd[i]);
      }
    }
  }
  const float Wc8[8] = {W8C0,W8C1,W8C2,W8C3,W8C4,W8C5,W8C6,W8C7};
  const float Ws8[8] = {W8S0,W8S1,W8S2,W8S3,W8S4,W8S5,W8S6,W8S7};
  float sb, cb2;
  sincosf(-3.14159265358979f * (float)t / (float)FFTN, &sb, &cb2);
  f2 cbase = mkf2(cb2, sb);
  for (int hh = 0; hh < 2; ++hh) {
    __syncthreads();   // prev readers of bufA done (cbs / odd-bin reads)
    #pragma unroll
    for (int i = 0; i < 8; ++i) {
      int l = t + i*NT;
      f2 fv = f2v[l], fc = facv[l];
      bufA[PSWZ(l)] = cmul(fv, k00[hh][i] - cmul(k01[hh][i], fc));
    }
    __syncthreads();
    f2* krow = Kf + (size_t)(h0 + hh) * KFS;
    #pragma unroll
    for (int i = 0; i < 4; ++i) {               // even bins: Hermitian part of at_roots
      int m = t + i*NT;
      if (m == 0) {
        krow[0]    = mkf2(bufA[0].x, 0.f);
        krow[FFTN] = mkf2(bufA[PSWZ(FFTN/2)].x, 0.f);
      } else {
        krow[2*m] = 0.5f * (bufA[PSWZ(m)] + cconj(bufA[PSWZ(FFTN - m)]));
      }
    }
    fft2048<true, false, false>(bufA, bufB, tw, t, st);   // iFFT (unscaled), result bufA
    const float scale = 1.0f / (float)FFTN;
    #pragma unroll
    for (int i = 0; i < 8; ++i) {               // twist in place (same addr per thread)
      int n = t + i*NT;
      float K = bufA[PSWZ(n)].x * scale;
      bufA[PSWZ(n)] = K * cmul(cbase, mkf2(Wc8[i], Ws8[i]));
    }
    fft2048<false, false, true>(bufA, bufB, tw, t, st);   // odd bins (lower half) in bufA
    #pragma unroll
    for (int i = 0; i < 4; ++i) {
      int m = t + i*NT;
      krow[2*m+1] = bufA[PSWZ(m)];
    }
  }
}

// Launch 3: per (b,h) row in rT: rfft4096 (packed) -> *Kf -> irfft4096 + D*r.
// Block swizzle: 8 consecutive blocks share one Kf row (h = bid>>3).
__global__ __launch_bounds__(NT, 4) void kconv(float* __restrict__ rT, const f2* __restrict__ Kf,
                                               const float* __restrict__ Dp)
{
  __shared__ f2 bufA[FFTN];
  __shared__ f2 bufB[FFTN];
  __shared__ f2 tw[256];
  int t = threadIdx.x, st = PSWZ(t);
  int h = blockIdx.x >> 3;
  int b = blockIdx.x & 7;
  float Dv = Dp[0];
  init_tw(tw, t);
  float* rrow = rT + ((size_t)b*SSM_H + h) * SSM_L;
  const float4* r4 = (const float4*)rrow;
  float4 vin[2];
  #pragma unroll
  for (int i = 0; i < 2; ++i) {                  // 2048 reals -> lower 1024 packed f2
    int j2 = t + i*NT;
    vin[i] = r4[j2];
    bufA[PSWZ(2*j2)]   = mkf2(vin[i].x, vin[i].y);
    bufA[PSWZ(2*j2+1)] = mkf2(vin[i].z, vin[i].w);
  }
  fft2048<false, true, false>(bufA, bufB, tw, t, st);   // spectrum in bufA
  const f2* krow = Kf + (size_t)h * KFS;
  float sb, cb;
  sincosf(-3.14159265358979f * (float)t / (float)FFTN, &sb, &cb);
  f2 base = mkf2(cb, sb);
  {
    const float Wc[4] = {W8C0,W8C1,W8C2,W8C3};
    const float Ws[4] = {W8S0,W8S1,W8S2,W8S3};
    #pragma unroll
    for (int i = 0; i < 4; ++i) {                // unpack -> *Kf -> repack into bufB
      int k = t + i*NT;
      f2 w = cmul(base, mkf2(Wc[i], Ws[i]));     // exp(-i*pi*k/2048)
      float c = w.x, s = w.y;
      if (k == 0) {
        f2 c0 = bufA[0];
        float F0 = c0.x + c0.y, Fn = c0.x - c0.y;
        f2 G0 = F0 * krow[0];
        f2 Gn = Fn * krow[FFTN];
        f2 Xe = 0.5f * (G0 + Gn);
        f2 Xo = 0.5f * (G0 - Gn);
        bufB[0] = mkf2(Xe.x - Xo.y, Xe.y + Xo.x);
        f2 Gm = cmul(cconj(bufA[PSWZ(FFTN/2)]), krow[FFTN/2]);
        bufB[PSWZ(FFTN/2)] = cconj(Gm);
      } else {
        int kk = FFTN - k;
        f2 Ck = bufA[PSWZ(k)], Ckk = bufA[PSWZ(kk)];
        f2 E = mkf2(0.5f*(Ck.x + Ckk.x), 0.5f*(Ck.y - Ckk.y));
        f2 O = mkf2(0.5f*(Ck.y + Ckk.y), 0.5f*(Ckk.x - Ck.x));
        f2 Fk  = E + cmul(mkf2(c, s), O);
        f2 Fkk = cconj(E) + cmul(mkf2(-c, s), cconj(O));
        f2 Gk  = cmul(Fk,  krow[k]);
        f2 Gkk = cmul(Fkk, krow[kk]);
        f2 Xe  = mkf2(0.5f*(Gk.x + Gkk.x), 0.5f*(Gk.y - Gkk.y));
        f2 Dd  = mkf2(0.5f*(Gk.x - Gkk.x), 0.5f*(Gk.y + Gkk.y));
        f2 Xo  = cmul(mkf2(c, -s), Dd);          // conj(w) * Dd
        bufB[PSWZ(k)] = mkf2(Xe.x - Xo.y, Xe.y + Xo.x);
        f2 Xe2 = mkf2(0.5f*(Gkk.x + Gk.x), 0.5f*(Gkk.y - Gk.y));
        f2 Dd2 = mkf2(0.5f*(Gkk.x - Gk.x), 0.5f*(Gkk.y + Gk.y));
        f2 Xo2 = cmul(mkf2(-c, -s), Dd2);        // -w * Dd2
        bufB[PSWZ(kk)] = mkf2(Xe2.x - Xo2.y, Xe2.y + Xo2.x);
      }
    }
  }
  fft2048<true, false, true>(bufB, bufA, tw, t, st);    // result (lower half) in bufB
  const float sc = 1.0f / (float)FFTN;
  float4* w4 = (float4*)rrow;
  #pragma unroll
  for (int i = 0; i < 2; ++i) {
    int j2 = t + i*NT;
    f2 z0 = bufB[PSWZ(2*j2)], z1 = bufB[PSWZ(2*j2+1)];
    w4[j2] = make_float4(z0.x*sc + Dv*vin[i].x, z0.y*sc + Dv*vin[i].y,
                         z1.x*sc + Dv*vin[i].z, z1.y*sc + Dv*vin[i].w);
  }
}

// Launch 4: (B,H,L) -> (B,L,H) transpose + exact GELU
__global__ __launch_bounds__(256) void ktback(const float* __restrict__ yT, float* __restrict__ out)
{
  __shared__ float til[64][65];
  int t = threadIdx.x, tx = t & 15, ty = t >> 4;
  int h0 = blockIdx.x * 64, l0 = blockIdx.y * 64, b = blockIdx.z;
  const float4* s4 = (const float4*)(yT + ((size_t)b*SSM_H + h0)*SSM_L + l0);
  #pragma unroll
  for (int i = 0; i < 4; ++i) {
    int hr = ty + 16*i;
    float4 v = s4[(size_t)hr*(SSM_L/4) + tx];
    til[hr][4*tx+0]=v.x; til[hr][4*tx+1]=v.y; til[hr][4*tx+2]=v.z; til[hr][4*tx+3]=v.w;
  }
  __syncthreads();
  float4* d4 = (float4*)(out + ((size_t)b*SSM_L + l0)*SSM_H + h0);
  #pragma unroll
  for (int i = 0; i < 4; ++i) {
    int lr = ty + 16*i;
    float4 w;
    float x0 = til[4*tx+0][lr], x1 = til[4*tx+1][lr];
    float x2 = til[4*tx+2][lr], x3 = til[4*tx+3][lr];
    w.x = 0.5f * x0 * (1.0f + erff(x0 * 0.70710678118654752f));
    w.y = 0.5f * x1 * (1.0f + erff(x1 * 0.70710678118654752f));
    w.z = 0.5f * x2 * (1.0f + erff(x2 * 0.70710678118654752f));
    w.w = 0.5f * x3 * (1.0f + erff(x3 * 0.70710678118654752f));
    d4[(size_t)lr*(SSM_H/4) + tx] = w;
  }
}

extern "C" void kernel_launch(void* const* d_in, const int* in_sizes, int n_in,
                              void* d_out, int out_size, void* d_ws, size_t ws_size,
                              hipStream_t stream)
{
  const float* r       = (const float*)d_in[0];
  const float* B_re    = (const float*)d_in[1];
  const float* B_im    = (const float*)d_in[2];
  const float* C_re    = (const float*)d_in[3];
  const float* C_im    = (const float*)d_in[4];
  const float* P_re    = (const float*)d_in[5];
  const float* P_im    = (const float*)d_in[6];
  const float* Q_re    = (const float*)d_in[7];
  const float* Q_im    = (const float*)d_in[8];
  const float* diag_re = (const float*)d_in[9];
  const float* diag_im = (const float*)d_in[10];
  const float* step    = (const float*)d_in[11];
  const float* Dp      = (const float*)d_in[12];
  float* out = (float*)d_out;

  char* p = (char*)d_ws;
  float* rT  = (float*)p; p += (size_t)SSM_B*SSM_H*SSM_L*sizeof(float);   // 64 MiB
  f2* cdenT  = (f2*)p;    p += (size_t)SSM_N*SSM_L*sizeof(f2);            // 1 MiB
  f2* f2v    = (f2*)p;    p += (size_t)SSM_L*sizeof(f2);
  f2* facv   = (f2*)p;    p += (size_t)SSM_L*sizeof(f2);
  f2* Kf     = (f2*)p;    p += (size_t)SSM_H*KFS*sizeof(f2);              // ~16.8 MiB

  kprep<<<4096 + 64, 256, 0, stream>>>(r, rT, B_re, B_im, P_re, P_im, Q_re, Q_im,
                                       diag_re, diag_im, step, cdenT, f2v, facv);
  kkern<<<SSM_H/2, NT, 0, stream>>>(C_re, C_im, B_re, B_im, P_re, P_im,
                                    cdenT, f2v, facv, Kf);
  kconv<<<SSM_B*SSM_H, NT, 0, stream>>>(rT, Kf, Dp);
  ktback<<<dim3(SSM_H/64, SSM_L/64, SSM_B), 256, 0, stream>>>(rT, out);
}